// Round 12
// baseline (310.385 us; speedup 1.0000x reference)
//
#include <hip/hip_runtime.h>
#include <hip/hip_bf16.h>
#include <cstdint>
#include <cstddef>

#define B_   4
#define T_   4096
#define C_   1024
#define H_   16
#define NC_  64
#define M_   (B_*T_)     // 16384 rows
#define N3_  (3*C_)      // 3072
#define NT2  32          // K=1024 / BK=32

typedef __attribute__((ext_vector_type(4))) float  f32x4;
typedef __attribute__((ext_vector_type(8))) __bf16 bf16x8;
typedef __attribute__((ext_vector_type(4))) __bf16 bf16x4;
typedef __attribute__((ext_vector_type(8))) unsigned short u16x8;

__device__ __forceinline__ void glds16(void* lds, const void* g) {
  __builtin_amdgcn_global_load_lds((const __attribute__((address_space(1))) void*)g,
                                   (__attribute__((address_space(3))) void*)lds,
                                   16, 0, 0);
}
#define MFMA_BF16 __builtin_amdgcn_mfma_f32_16x16x32_bf16

// ---------------- fp32 -> bf16 ----------------
__global__ __launch_bounds__(256) void cvt_f32_bf16(const float* __restrict__ in,
                                                    __bf16* __restrict__ out, int n4) {
  int i = blockIdx.x * 256 + threadIdx.x;
  if (i >= n4) return;
  float4 v = reinterpret_cast<const float4*>(in)[i];
  bf16x4 o;
  o[0] = (__bf16)v.x; o[1] = (__bf16)v.y; o[2] = (__bf16)v.z; o[3] = (__bf16)v.w;
  reinterpret_cast<bf16x4*>(out)[i] = o;
}

// ---------------- RoPE cos/sin table ----------------
__global__ __launch_bounds__(256) void rope_tab(float2* __restrict__ tab) {
  int gid = blockIdx.x * 256 + threadIdx.x;  // 131072 entries
  int t = gid >> 5, dp = gid & 31;
  float invf = exp2f(-(float)dp * (13.287712379549449f / 32.0f));
  float ang = (float)t * invf;
  float s, c;
  sincosf(ang, &s, &c);
  tab[gid] = make_float2(c, s);
}

// ============ 256x256 GEMM: C = A @ Bt^T, BK=32, 4-buf pipeline, vmcnt(8), ============
// ============ 8 waves 2Mx4N each 128x64 (2.67 MFMA/ds_read), T2 swizzle      ============
// FUSE==1: bf16 out + rope/relu on q,k col-blocks (bn<8).  FUSE==2: fp32 out.
// grid (N/256, 64), 512 threads. K fixed 1024.
template<int FUSE>
__global__ __launch_bounds__(512) void gemm_pipe256(const __bf16* __restrict__ A,
                                                    const __bf16* __restrict__ Bt,
                                                    void* __restrict__ Cout,
                                                    const float2* __restrict__ tab,
                                                    int N) {
  __shared__ __bf16 sA[4][256 * 32];   // 4 x 16 KB, [row][32k] rows of 64B = 4 slots
  __shared__ __bf16 sB[4][256 * 32];
  const int tid  = threadIdx.x;
  const int lane = tid & 63;
  const int wave = tid >> 6;
  const int wm = wave >> 2, wn = wave & 3;   // 2 x 4 waves, each 128x64
  const int bm = blockIdx.y, bn = blockIdx.x;
  const int fr = lane & 15, kq = lane >> 4;
  const int K = C_;

  // staging: per issue 512 thr x 16B = 8KB = 128 rows x 64B. Linear LDS dest,
  // inverse-swizzled global source slot: s = (tid&3) ^ (row&3).
  const int r_loc = tid >> 2;
  const int sslot = (tid & 3) ^ (r_loc & 3);
  const __bf16* Ag = A  + (size_t)(bm * 256 + r_loc) * K + sslot * 8;
  const __bf16* Bg = Bt + (size_t)(bn * 256 + r_loc) * K + sslot * 8;

  f32x4 acc[8][4];
#pragma unroll
  for (int i = 0; i < 8; i++)
#pragma unroll
    for (int j = 0; j < 4; j++) acc[i][j] = (f32x4)0.0f;

  // prologue: stage tiles 0,1,2 (4 issues each: A-rows0-127, A-rows128-255, B x2)
#pragma unroll
  for (int t = 0; t < 3; ++t) {
    glds16((char*)sA[t] +    0 + tid * 16, Ag + (size_t)0 * 128 * K + t * 32);
    glds16((char*)sA[t] + 8192 + tid * 16, Ag + (size_t)1 * 128 * K + t * 32);
    glds16((char*)sB[t] +    0 + tid * 16, Bg + (size_t)0 * 128 * K + t * 32);
    glds16((char*)sB[t] + 8192 + tid * 16, Bg + (size_t)1 * 128 * K + t * 32);
  }
  asm volatile("s_waitcnt vmcnt(8)" ::: "memory");  // tile0 resident; 1,2 in flight
  __builtin_amdgcn_sched_barrier(0);
  __builtin_amdgcn_s_barrier();

  const int swz = (kq ^ (fr & 3)) * 16;   // swizzled 16B slot within 64B row
  bf16x8 af[8], bf4[4];
  for (int t = 0; t < NT2; ++t) {
    const int buf  = t & 3;
    const int nbuf = (t + 3) & 3;          // == (t-1)&3, sealed by end-of-(t-1) barrier
    const __bf16* Ab = (const __bf16*)sA[buf];
    const __bf16* Bb = (const __bf16*)sB[buf];

    if (t + 3 < NT2) {                     // stage tile t+3 (4 issues, fly across MFMA)
      const int kb3 = (t + 3) * 32;
      glds16((char*)sA[nbuf] +    0 + tid * 16, Ag + (size_t)0 * 128 * K + kb3);
      glds16((char*)sA[nbuf] + 8192 + tid * 16, Ag + (size_t)1 * 128 * K + kb3);
      glds16((char*)sB[nbuf] +    0 + tid * 16, Bg + (size_t)0 * 128 * K + kb3);
      glds16((char*)sB[nbuf] + 8192 + tid * 16, Bg + (size_t)1 * 128 * K + kb3);
    }

    // 12 x ds_read_b128 -> 32 MFMA
#pragma unroll
    for (int i = 0; i < 8; ++i)
      af[i] = *(const bf16x8*)((const char*)Ab + (wm * 128 + i * 16 + fr) * 64 + swz);
#pragma unroll
    for (int j = 0; j < 4; ++j)
      bf4[j] = *(const bf16x8*)((const char*)Bb + (wn * 64 + j * 16 + fr) * 64 + swz);

    __builtin_amdgcn_s_setprio(1);
#pragma unroll
    for (int i = 0; i < 8; ++i)
#pragma unroll
      for (int j = 0; j < 4; ++j)
        acc[i][j] = MFMA_BF16(af[i], bf4[j], acc[i][j], 0, 0, 0);
    __builtin_amdgcn_s_setprio(0);

    // boundary: t+1 must be resident; newer tiles' loads may stay in flight
    if (t < NT2 - 1) {
      if (t < NT2 - 3)       asm volatile("s_waitcnt vmcnt(8)" ::: "memory");
      else if (t == NT2 - 3) asm volatile("s_waitcnt vmcnt(4)" ::: "memory");
      else                   asm volatile("s_waitcnt vmcnt(0)" ::: "memory");
      __builtin_amdgcn_sched_barrier(0);
      __builtin_amdgcn_s_barrier();
    }
  }

  // epilogue
  const int rg4 = kq * 4;
  const int cb = bn * 256 + wn * 64;
  if (FUSE == 1 && bn < 8) {
    // q/k block: rope + relu; pair (d, d+32) = (j, j+2) in-lane
#pragma unroll
    for (int i = 0; i < 8; ++i)
#pragma unroll
      for (int r = 0; r < 4; ++r) {
        size_t row = (size_t)bm * 256 + wm * 128 + i * 16 + rg4 + r;
        int tt = (int)(row & (T_ - 1));
#pragma unroll
        for (int j = 0; j < 2; ++j) {
          int dp = j * 16 + fr;
          float2 cs = tab[tt * 32 + dp];
          float x1 = acc[i][j][r], x2 = acc[i][j + 2][r];
          float o1 = fmaxf(x1 * cs.x - x2 * cs.y, 0.0f);
          float o2 = fmaxf(x2 * cs.x + x1 * cs.y, 0.0f);
          ((__bf16*)Cout)[row * N + cb + j * 16 + fr]      = (__bf16)o1;
          ((__bf16*)Cout)[row * N + cb + j * 16 + fr + 32] = (__bf16)o2;
        }
      }
  } else {
#pragma unroll
    for (int i = 0; i < 8; ++i)
#pragma unroll
      for (int j = 0; j < 4; ++j) {
        size_t row = (size_t)bm * 256 + wm * 128 + i * 16 + rg4;
        size_t col = (size_t)cb + j * 16 + fr;
#pragma unroll
        for (int r = 0; r < 4; ++r) {
          if (FUSE == 2) ((float*)Cout)[(row + r) * N + col]  = acc[i][j][r];
          else           ((__bf16*)Cout)[(row + r) * N + col] = (__bf16)acc[i][j][r];
        }
      }
  }
}

// ---------------- stage A: G_c = K_c^T V_c per (b,h,chunk) ----------------
#define LDW 72
__global__ __launch_bounds__(256) void chunk_kv(const __bf16* __restrict__ qkv,
                                                __bf16* __restrict__ G) {
  __shared__ __bf16 Kt[64 * LDW];
  __shared__ __bf16 Vt[64 * LDW];
  const int bid = blockIdx.x;
  const int c = bid & (NC_ - 1);
  const int bh = bid >> 6;
  const int h = bh & (H_ - 1);
  const int b = bh >> 4;
  const int tid = threadIdx.x;
  const size_t row0 = (size_t)b * T_ + c * 64;
  const int kcol = C_ + h * 64;
  const int vcol = 2 * C_ + h * 64;
#pragma unroll
  for (int it = 0; it < 2; ++it) {
    int task = tid + it * 256;
    int t = task >> 3;
    int d0 = (task & 7) * 8;
    const size_t rb = (row0 + t) * N3_;
    u16x8 kv = *(const u16x8*)(qkv + rb + kcol + d0);
    u16x8 vv = *(const u16x8*)(qkv + rb + vcol + d0);
#pragma unroll
    for (int j = 0; j < 8; j++) {
      ((unsigned short*)Kt)[(d0 + j) * LDW + t] = kv[j];
      ((unsigned short*)Vt)[(d0 + j) * LDW + t] = vv[j];
    }
  }
  __syncthreads();
  const int lane = tid & 63, wave = tid >> 6;
  const int gr = (wave >> 1) * 32, gc = (wave & 1) * 32;
  const int fr = lane & 15, kb = (lane >> 4) * 8;
  f32x4 acc[2][2];
#pragma unroll
  for (int i = 0; i < 2; i++)
#pragma unroll
    for (int j = 0; j < 2; j++) acc[i][j] = (f32x4)0.0f;
#pragma unroll
  for (int kk = 0; kk < 2; ++kk) {
    bf16x8 af[2], bfr[2];
#pragma unroll
    for (int i = 0; i < 2; i++)
      af[i] = *(const bf16x8*)(Kt + (gr + i * 16 + fr) * LDW + kk * 32 + kb);
#pragma unroll
    for (int j = 0; j < 2; j++)
      bfr[j] = *(const bf16x8*)(Vt + (gc + j * 16 + fr) * LDW + kk * 32 + kb);
#pragma unroll
    for (int i = 0; i < 2; i++)
#pragma unroll
      for (int j = 0; j < 2; j++)
        acc[i][j] = MFMA_BF16(af[i], bfr[j], acc[i][j], 0, 0, 0);
  }
  const int rg = (lane >> 4) * 4;
  __bf16* Gb = G + (size_t)bid * 4096;
#pragma unroll
  for (int i = 0; i < 2; i++)
#pragma unroll
    for (int j = 0; j < 2; j++)
#pragma unroll
      for (int r = 0; r < 4; r++)
        Gb[(gr + i * 16 + rg + r) * 64 + gc + j * 16 + fr] = (__bf16)acc[i][j][r];
}

// ---------------- stage B: prefix over chunks ----------------
__global__ __launch_bounds__(256) void prefix_scan(const __bf16* __restrict__ G,
                                                   const float* __restrict__ sigma0,
                                                   __bf16* __restrict__ S,
                                                   float* __restrict__ sigma_out,
                                                   const float* __restrict__ eta) {
  const int blk = blockIdx.x;       // 0..255
  const int bh = blk >> 2;
  const int dq = blk & 3;
  const int tid = threadIdx.x;
  const int d = dq * 16 + (tid >> 4);
  const int e0 = (tid & 15) * 4;
  const float eta_s = eta[0];
  const size_t base_de = (size_t)d * 64 + e0;
  float acc[4], s0[4];
#pragma unroll
  for (int j = 0; j < 4; j++) {
    acc[j] = 0.0f;
    s0[j] = sigma0[(size_t)bh * 4096 + base_de + j];
  }
  for (int c = 0; c < NC_; ++c) {
    const size_t off = ((size_t)bh * NC_ + c) * 4096 + base_de;
    bf16x4 sv;
#pragma unroll
    for (int j = 0; j < 4; j++) sv[j] = (__bf16)(s0[j] + eta_s * acc[j]);
    *(bf16x4*)(S + off) = sv;
    bf16x4 g = *(const bf16x4*)(G + off);
#pragma unroll
    for (int j = 0; j < 4; j++) acc[j] += (float)g[j];
  }
  float4 v;
  v.x = s0[0] + eta_s * acc[0];
  v.y = s0[1] + eta_s * acc[1];
  v.z = s0[2] + eta_s * acc[2];
  v.w = s0[3] + eta_s * acc[3];
  *reinterpret_cast<float4*>(sigma_out + (size_t)bh * 4096 + base_de) = v;
}

// ---------------- stage C: O = eta*strict_tril(Q K^T) V + Q S_c ----------------
__global__ __launch_bounds__(256) void chunk_out(const __bf16* __restrict__ qkv,
                                                 const __bf16* __restrict__ S,
                                                 __bf16* __restrict__ outp,
                                                 const float* __restrict__ eta) {
  __shared__ __bf16 Qs[64 * LDW];
  __shared__ __bf16 Ks[64 * LDW];
  __shared__ __bf16 Vt[64 * LDW];
  __shared__ __bf16 St[64 * LDW];
  __shared__ __bf16 Ps[64 * LDW];
  const int bid = blockIdx.x;
  const int c = bid & 63, bh = bid >> 6, h = bh & 15, b = bh >> 4;
  const int tid = threadIdx.x;
  const size_t row0 = (size_t)b * T_ + c * 64;
  const float eta_s = eta[0];
#pragma unroll
  for (int it = 0; it < 2; ++it) {
    int task = tid + it * 256;
    int t = task >> 3, d0 = (task & 7) * 8;
    const size_t rb = (row0 + t) * N3_;
    *(u16x8*)(Qs + t * LDW + d0) = *(const u16x8*)(qkv + rb + h * 64 + d0);
    *(u16x8*)(Ks + t * LDW + d0) = *(const u16x8*)(qkv + rb + C_ + h * 64 + d0);
    u16x8 vv = *(const u16x8*)(qkv + rb + 2 * C_ + h * 64 + d0);
    u16x8 sv = *(const u16x8*)(S + (size_t)bid * 4096 + t * 64 + d0);
#pragma unroll
    for (int j = 0; j < 8; j++) {
      ((unsigned short*)Vt)[(d0 + j) * LDW + t] = vv[j];
      ((unsigned short*)St)[(d0 + j) * LDW + t] = sv[j];
    }
  }
  __syncthreads();
  const int lane = tid & 63, wave = tid >> 6;
  const int qr = (wave >> 1) * 32, qc = (wave & 1) * 32;
  const int fr = lane & 15, kb = (lane >> 4) * 8, rg = (lane >> 4) * 4;
  {
    f32x4 pacc[2][2];
#pragma unroll
    for (int i = 0; i < 2; i++)
#pragma unroll
      for (int j = 0; j < 2; j++) pacc[i][j] = (f32x4)0.0f;
#pragma unroll
    for (int kk = 0; kk < 2; ++kk) {
      bf16x8 af[2], bfr[2];
#pragma unroll
      for (int i = 0; i < 2; i++)
        af[i] = *(const bf16x8*)(Qs + (qr + i * 16 + fr) * LDW + kk * 32 + kb);
#pragma unroll
      for (int j = 0; j < 2; j++)
        bfr[j] = *(const bf16x8*)(Ks + (qc + j * 16 + fr) * LDW + kk * 32 + kb);
#pragma unroll
      for (int i = 0; i < 2; i++)
#pragma unroll
        for (int j = 0; j < 2; j++)
          pacc[i][j] = MFMA_BF16(af[i], bfr[j], pacc[i][j], 0, 0, 0);
    }
#pragma unroll
    for (int i = 0; i < 2; i++)
#pragma unroll
      for (int j = 0; j < 2; j++)
#pragma unroll
        for (int r = 0; r < 4; r++) {
          int trow = qr + i * 16 + rg + r;
          int scol = qc + j * 16 + fr;
          float v = (scol < trow) ? eta_s * pacc[i][j][r] : 0.0f;
          Ps[trow * LDW + scol] = (__bf16)v;
        }
  }
  __syncthreads();
  {
    f32x4 oacc[2][2];
#pragma unroll
    for (int i = 0; i < 2; i++)
#pragma unroll
      for (int j = 0; j < 2; j++) oacc[i][j] = (f32x4)0.0f;
#pragma unroll
    for (int kk = 0; kk < 2; ++kk) {
      bf16x8 pa[2], vb[2], qa[2], sb[2];
#pragma unroll
      for (int i = 0; i < 2; i++) {
        pa[i] = *(const bf16x8*)(Ps + (qr + i * 16 + fr) * LDW + kk * 32 + kb);
        qa[i] = *(const bf16x8*)(Qs + (qr + i * 16 + fr) * LDW + kk * 32 + kb);
      }
#pragma unroll
      for (int j = 0; j < 2; j++) {
        vb[j] = *(const bf16x8*)(Vt + (qc + j * 16 + fr) * LDW + kk * 32 + kb);
        sb[j] = *(const bf16x8*)(St + (qc + j * 16 + fr) * LDW + kk * 32 + kb);
      }
#pragma unroll
      for (int i = 0; i < 2; i++)
#pragma unroll
        for (int j = 0; j < 2; j++) {
          oacc[i][j] = MFMA_BF16(pa[i], vb[j], oacc[i][j], 0, 0, 0);
          oacc[i][j] = MFMA_BF16(qa[i], sb[j], oacc[i][j], 0, 0, 0);
        }
    }
#pragma unroll
    for (int i = 0; i < 2; i++)
#pragma unroll
      for (int j = 0; j < 2; j++)
#pragma unroll
        for (int r = 0; r < 4; r++) {
          size_t row = row0 + qr + i * 16 + rg + r;
          int col = h * 64 + qc + j * 16 + fr;
          outp[row * C_ + col] = (__bf16)oacc[i][j][r];
        }
  }
}

extern "C" void kernel_launch(void* const* d_in, const int* in_sizes, int n_in,
                              void* d_out, int out_size, void* d_ws, size_t ws_size,
                              hipStream_t stream) {
  const float* x      = (const float*)d_in[0];
  const float* sigma0 = (const float*)d_in[1];
  const float* w_qkv  = (const float*)d_in[2];
  const float* w_proj = (const float*)d_in[3];
  const float* eta    = (const float*)d_in[4];
  float* out       = (float*)d_out;
  float* sigma_out = out + (size_t)M_ * C_;

  char* ws = (char*)d_ws;
  __bf16* xbf     = (__bf16*)(ws);               // 32 MB (reused as out_pre)
  __bf16* wqkvbf  = (__bf16*)(ws + 33554432);
  __bf16* wprojbf = (__bf16*)(ws + 39845888);
  __bf16* qkvbf   = (__bf16*)(ws + 41943040);    // 96 MB
  __bf16* Gws     = (__bf16*)(ws + 142606336);   // 32 MB
  __bf16* Sws     = (__bf16*)(ws + 176160768);   // 32 MB
  float2* tab     = (float2*)(ws + 176160768);   // 1 MB, dead before prefix_scan writes S

  rope_tab<<<512, 256, 0, stream>>>(tab);
  cvt_f32_bf16<<<16384, 256, 0, stream>>>(x, xbf, 4194304);
  cvt_f32_bf16<<<3072, 256, 0, stream>>>(w_qkv, wqkvbf, 786432);
  cvt_f32_bf16<<<1024, 256, 0, stream>>>(w_proj, wprojbf, 262144);
  gemm_pipe256<1><<<dim3(12, 64), 512, 0, stream>>>(xbf, wqkvbf, (void*)qkvbf, tab, N3_);
  chunk_kv<<<4096, 256, 0, stream>>>(qkvbf, Gws);
  prefix_scan<<<256, 256, 0, stream>>>(Gws, sigma0, Sws, sigma_out, eta);
  chunk_out<<<4096, 256, 0, stream>>>(qkvbf, Sws, xbf, eta);
  gemm_pipe256<2><<<dim3(4, 64), 512, 0, stream>>>(xbf, wprojbf, (void*)out, nullptr, C_);
}

// Round 14
// 267.732 us; speedup vs baseline: 1.1593x; 1.1593x over previous
//
#include <hip/hip_runtime.h>
#include <hip/hip_bf16.h>
#include <cstdint>
#include <cstddef>

#define B_   4
#define T_   4096
#define C_   1024
#define H_   16
#define NC_  64
#define M_   (B_*T_)     // 16384 rows
#define N3_  (3*C_)      // 3072
#define NTK  16          // K=1024 / BK=64

typedef __attribute__((ext_vector_type(4))) float  f32x4;
typedef __attribute__((ext_vector_type(8))) __bf16 bf16x8;
typedef __attribute__((ext_vector_type(4))) __bf16 bf16x4;
typedef __attribute__((ext_vector_type(8))) unsigned short u16x8;

__device__ __forceinline__ void glds16(void* lds, const void* g) {
  __builtin_amdgcn_global_load_lds((const __attribute__((address_space(1))) void*)g,
                                   (__attribute__((address_space(3))) void*)lds,
                                   16, 0, 0);
}
#define MFMA_BF16 __builtin_amdgcn_mfma_f32_16x16x32_bf16

// ---------------- fp32 -> bf16 ----------------
__global__ __launch_bounds__(256) void cvt_f32_bf16(const float* __restrict__ in,
                                                    __bf16* __restrict__ out, int n4) {
  int i = blockIdx.x * 256 + threadIdx.x;
  if (i >= n4) return;
  float4 v = reinterpret_cast<const float4*>(in)[i];
  bf16x4 o;
  o[0] = (__bf16)v.x; o[1] = (__bf16)v.y; o[2] = (__bf16)v.z; o[3] = (__bf16)v.w;
  reinterpret_cast<bf16x4*>(out)[i] = o;
}

// ---------------- RoPE cos/sin table ----------------
__global__ __launch_bounds__(256) void rope_tab(float2* __restrict__ tab) {
  int gid = blockIdx.x * 256 + threadIdx.x;  // 131072 entries
  int t = gid >> 5, dp = gid & 31;
  float invf = exp2f(-(float)dp * (13.287712379549449f / 32.0f));
  float ang = (float)t * invf;
  float s, c;
  sincosf(ang, &s, &c);
  tab[gid] = make_float2(c, s);
}

// ============ 256x256 GEMM, BK=64, 2-buf double-buffer, 1 barrier/tile.      ============
// ============ 8 waves 2Mx4N each 128x64: 24 ds_read_b128 / 64 MFMA (2.67).   ============
// ============ 128B LDS rows, 8-slot XOR swizzle (proven 0-conflict, r10).    ============
// FUSE==1: bf16 out + rope/relu on q,k col-blocks (bn<8).  FUSE==2: fp32 out.
// grid (N/256, 64), 512 threads. K fixed 1024.
template<int FUSE>
__global__ __launch_bounds__(512) void gemm_dbuf(const __bf16* __restrict__ A,
                                                 const __bf16* __restrict__ Bt,
                                                 void* __restrict__ Cout,
                                                 const float2* __restrict__ tab,
                                                 int N) {
  __shared__ __bf16 sA[2][256 * 64];   // 2 x 32 KB, [row][64k], rows of 128B = 8 slots
  __shared__ __bf16 sB[2][256 * 64];
  const int tid  = threadIdx.x;
  const int lane = tid & 63;
  const int wave = tid >> 6;
  const int wm = wave >> 2, wn = wave & 3;   // 2 x 4 waves, each 128x64
  const int bm = blockIdx.y, bn = blockIdx.x;
  const int fr = lane & 15, kq = lane >> 4;
  const int fr7 = fr & 7;
  const int K = C_;

  // staging: per issue 512 thr x 16B = 8KB = 64 rows x 128B. Linear LDS dest,
  // inverse-swizzled global source slot: s = (tid&7) ^ (row&7).
  const int r_loc = tid >> 3;
  const int sslot = (tid & 7) ^ (r_loc & 7);
  const __bf16* Ag = A  + (size_t)(bm * 256 + r_loc) * K + sslot * 8;
  const __bf16* Bg = Bt + (size_t)(bn * 256 + r_loc) * K + sslot * 8;

  f32x4 acc[8][4];
#pragma unroll
  for (int i = 0; i < 8; i++)
#pragma unroll
    for (int j = 0; j < 4; j++) acc[i][j] = (f32x4)0.0f;

  // prologue: stage tile 0 (8 issues of 8KB)
#pragma unroll
  for (int q = 0; q < 4; ++q) {
    glds16((char*)sA[0] + q * 8192 + tid * 16, Ag + (size_t)q * 64 * K);
    glds16((char*)sB[0] + q * 8192 + tid * 16, Bg + (size_t)q * 64 * K);
  }
  asm volatile("s_waitcnt vmcnt(0)" ::: "memory");
  __builtin_amdgcn_sched_barrier(0);
  __builtin_amdgcn_s_barrier();

  bf16x8 af[4][2], bfr[4][2];
  for (int t = 0; t < NTK; ++t) {
    const int buf = t & 1, nb = buf ^ 1;
    const __bf16* Ab = (const __bf16*)sA[buf];
    const __bf16* Bb = (const __bf16*)sB[buf];

    // stage tile t+1 into the other buffer (its last readers sealed by prior barrier)
    if (t + 1 < NTK) {
      const int kb = (t + 1) * 64;
#pragma unroll
      for (int q = 0; q < 4; ++q) {
        glds16((char*)sA[nb] + q * 8192 + tid * 16, Ag + (size_t)q * 64 * K + kb);
        glds16((char*)sB[nb] + q * 8192 + tid * 16, Bg + (size_t)q * 64 * K + kb);
      }
    }

    // B fragments (8 reads), then two A-halves of 8 reads + 32 MFMA each
#pragma unroll
    for (int j = 0; j < 4; ++j)
#pragma unroll
      for (int kk = 0; kk < 2; ++kk)
        bfr[j][kk] = *(const bf16x8*)((const char*)Bb + (wn * 64 + j * 16 + fr) * 128 +
                                      (((kk << 2) | kq) ^ fr7) * 16);
#pragma unroll
    for (int h = 0; h < 2; ++h) {
#pragma unroll
      for (int i = 0; i < 4; ++i)
#pragma unroll
        for (int kk = 0; kk < 2; ++kk)
          af[i][kk] = *(const bf16x8*)((const char*)Ab +
                        (wm * 128 + (h * 4 + i) * 16 + fr) * 128 +
                        (((kk << 2) | kq) ^ fr7) * 16);
      __builtin_amdgcn_s_setprio(1);
#pragma unroll
      for (int i = 0; i < 4; ++i)
#pragma unroll
        for (int j = 0; j < 4; ++j) {
          acc[h * 4 + i][j] = MFMA_BF16(af[i][0], bfr[j][0], acc[h * 4 + i][j], 0, 0, 0);
          acc[h * 4 + i][j] = MFMA_BF16(af[i][1], bfr[j][1], acc[h * 4 + i][j], 0, 0, 0);
        }
      __builtin_amdgcn_s_setprio(0);
    }

    if (t < NTK - 1) {
      asm volatile("s_waitcnt vmcnt(0)" ::: "memory");  // tile t+1 landed
      __builtin_amdgcn_sched_barrier(0);
      __builtin_amdgcn_s_barrier();
    }
  }

  // epilogue
  const int rg4 = kq * 4;
  const int cb = bn * 256 + wn * 64;
  if (FUSE == 1 && bn < 8) {
    // q/k block: rope + relu; pair (d, d+32) = (j, j+2) in-lane
#pragma unroll
    for (int i = 0; i < 8; ++i)
#pragma unroll
      for (int r = 0; r < 4; ++r) {
        size_t row = (size_t)bm * 256 + wm * 128 + i * 16 + rg4 + r;
        int tt = (int)(row & (T_ - 1));
#pragma unroll
        for (int j = 0; j < 2; ++j) {
          int dp = j * 16 + fr;
          float2 cs = tab[tt * 32 + dp];
          float x1 = acc[i][j][r], x2 = acc[i][j + 2][r];
          float o1 = fmaxf(x1 * cs.x - x2 * cs.y, 0.0f);
          float o2 = fmaxf(x2 * cs.x + x1 * cs.y, 0.0f);
          ((__bf16*)Cout)[row * N + cb + j * 16 + fr]      = (__bf16)o1;
          ((__bf16*)Cout)[row * N + cb + j * 16 + fr + 32] = (__bf16)o2;
        }
      }
  } else {
#pragma unroll
    for (int i = 0; i < 8; ++i)
#pragma unroll
      for (int j = 0; j < 4; ++j) {
        size_t row = (size_t)bm * 256 + wm * 128 + i * 16 + rg4;
        size_t col = (size_t)cb + j * 16 + fr;
#pragma unroll
        for (int r = 0; r < 4; ++r) {
          if (FUSE == 2) ((float*)Cout)[(row + r) * N + col]  = acc[i][j][r];
          else           ((__bf16*)Cout)[(row + r) * N + col] = (__bf16)acc[i][j][r];
        }
      }
  }
}

// ---------------- stage A: G_c = K_c^T V_c per (b,h,chunk) ----------------
#define LDW 72
__global__ __launch_bounds__(256) void chunk_kv(const __bf16* __restrict__ qkv,
                                                __bf16* __restrict__ G) {
  __shared__ __bf16 Kt[64 * LDW];
  __shared__ __bf16 Vt[64 * LDW];
  const int bid = blockIdx.x;
  const int c = bid & (NC_ - 1);
  const int bh = bid >> 6;
  const int h = bh & (H_ - 1);
  const int b = bh >> 4;
  const int tid = threadIdx.x;
  const size_t row0 = (size_t)b * T_ + c * 64;
  const int kcol = C_ + h * 64;
  const int vcol = 2 * C_ + h * 64;
#pragma unroll
  for (int it = 0; it < 2; ++it) {
    int task = tid + it * 256;
    int t = task >> 3;
    int d0 = (task & 7) * 8;
    const size_t rb = (row0 + t) * N3_;
    u16x8 kv = *(const u16x8*)(qkv + rb + kcol + d0);
    u16x8 vv = *(const u16x8*)(qkv + rb + vcol + d0);
#pragma unroll
    for (int j = 0; j < 8; j++) {
      ((unsigned short*)Kt)[(d0 + j) * LDW + t] = kv[j];
      ((unsigned short*)Vt)[(d0 + j) * LDW + t] = vv[j];
    }
  }
  __syncthreads();
  const int lane = tid & 63, wave = tid >> 6;
  const int gr = (wave >> 1) * 32, gc = (wave & 1) * 32;
  const int fr = lane & 15, kb = (lane >> 4) * 8;
  f32x4 acc[2][2];
#pragma unroll
  for (int i = 0; i < 2; i++)
#pragma unroll
    for (int j = 0; j < 2; j++) acc[i][j] = (f32x4)0.0f;
#pragma unroll
  for (int kk = 0; kk < 2; ++kk) {
    bf16x8 af[2], bfr[2];
#pragma unroll
    for (int i = 0; i < 2; i++)
      af[i] = *(const bf16x8*)(Kt + (gr + i * 16 + fr) * LDW + kk * 32 + kb);
#pragma unroll
    for (int j = 0; j < 2; j++)
      bfr[j] = *(const bf16x8*)(Vt + (gc + j * 16 + fr) * LDW + kk * 32 + kb);
#pragma unroll
    for (int i = 0; i < 2; i++)
#pragma unroll
      for (int j = 0; j < 2; j++)
        acc[i][j] = MFMA_BF16(af[i], bfr[j], acc[i][j], 0, 0, 0);
  }
  const int rg = (lane >> 4) * 4;
  __bf16* Gb = G + (size_t)bid * 4096;
#pragma unroll
  for (int i = 0; i < 2; i++)
#pragma unroll
    for (int j = 0; j < 2; j++)
#pragma unroll
      for (int r = 0; r < 4; r++)
        Gb[(gr + i * 16 + rg + r) * 64 + gc + j * 16 + fr] = (__bf16)acc[i][j][r];
}

// ---------------- stage B: prefix over chunks ----------------
__global__ __launch_bounds__(256) void prefix_scan(const __bf16* __restrict__ G,
                                                   const float* __restrict__ sigma0,
                                                   __bf16* __restrict__ S,
                                                   float* __restrict__ sigma_out,
                                                   const float* __restrict__ eta) {
  const int blk = blockIdx.x;       // 0..255
  const int bh = blk >> 2;
  const int dq = blk & 3;
  const int tid = threadIdx.x;
  const int d = dq * 16 + (tid >> 4);
  const int e0 = (tid & 15) * 4;
  const float eta_s = eta[0];
  const size_t base_de = (size_t)d * 64 + e0;
  float acc[4], s0[4];
#pragma unroll
  for (int j = 0; j < 4; j++) {
    acc[j] = 0.0f;
    s0[j] = sigma0[(size_t)bh * 4096 + base_de + j];
  }
  for (int c = 0; c < NC_; ++c) {
    const size_t off = ((size_t)bh * NC_ + c) * 4096 + base_de;
    bf16x4 sv;
#pragma unroll
    for (int j = 0; j < 4; j++) sv[j] = (__bf16)(s0[j] + eta_s * acc[j]);
    *(bf16x4*)(S + off) = sv;
    bf16x4 g = *(const bf16x4*)(G + off);
#pragma unroll
    for (int j = 0; j < 4; j++) acc[j] += (float)g[j];
  }
  float4 v;
  v.x = s0[0] + eta_s * acc[0];
  v.y = s0[1] + eta_s * acc[1];
  v.z = s0[2] + eta_s * acc[2];
  v.w = s0[3] + eta_s * acc[3];
  *reinterpret_cast<float4*>(sigma_out + (size_t)bh * 4096 + base_de) = v;
}

// ---------------- stage C: O = eta*strict_tril(Q K^T) V + Q S_c ----------------
__global__ __launch_bounds__(256) void chunk_out(const __bf16* __restrict__ qkv,
                                                 const __bf16* __restrict__ S,
                                                 __bf16* __restrict__ outp,
                                                 const float* __restrict__ eta) {
  __shared__ __bf16 Qs[64 * LDW];
  __shared__ __bf16 Ks[64 * LDW];
  __shared__ __bf16 Vt[64 * LDW];
  __shared__ __bf16 St[64 * LDW];
  __shared__ __bf16 Ps[64 * LDW];
  const int bid = blockIdx.x;
  const int c = bid & 63, bh = bid >> 6, h = bh & 15, b = bh >> 4;
  const int tid = threadIdx.x;
  const size_t row0 = (size_t)b * T_ + c * 64;
  const float eta_s = eta[0];
#pragma unroll
  for (int it = 0; it < 2; ++it) {
    int task = tid + it * 256;
    int t = task >> 3, d0 = (task & 7) * 8;
    const size_t rb = (row0 + t) * N3_;
    *(u16x8*)(Qs + t * LDW + d0) = *(const u16x8*)(qkv + rb + h * 64 + d0);
    *(u16x8*)(Ks + t * LDW + d0) = *(const u16x8*)(qkv + rb + C_ + h * 64 + d0);
    u16x8 vv = *(const u16x8*)(qkv + rb + 2 * C_ + h * 64 + d0);
    u16x8 sv = *(const u16x8*)(S + (size_t)bid * 4096 + t * 64 + d0);
#pragma unroll
    for (int j = 0; j < 8; j++) {
      ((unsigned short*)Vt)[(d0 + j) * LDW + t] = vv[j];
      ((unsigned short*)St)[(d0 + j) * LDW + t] = sv[j];
    }
  }
  __syncthreads();
  const int lane = tid & 63, wave = tid >> 6;
  const int qr = (wave >> 1) * 32, qc = (wave & 1) * 32;
  const int fr = lane & 15, kb = (lane >> 4) * 8, rg = (lane >> 4) * 4;
  {
    f32x4 pacc[2][2];
#pragma unroll
    for (int i = 0; i < 2; i++)
#pragma unroll
      for (int j = 0; j < 2; j++) pacc[i][j] = (f32x4)0.0f;
#pragma unroll
    for (int kk = 0; kk < 2; ++kk) {
      bf16x8 af[2], bfr[2];
#pragma unroll
      for (int i = 0; i < 2; i++)
        af[i] = *(const bf16x8*)(Qs + (qr + i * 16 + fr) * LDW + kk * 32 + kb);
#pragma unroll
      for (int j = 0; j < 2; j++)
        bfr[j] = *(const bf16x8*)(Ks + (qc + j * 16 + fr) * LDW + kk * 32 + kb);
#pragma unroll
      for (int i = 0; i < 2; i++)
#pragma unroll
        for (int j = 0; j < 2; j++)
          pacc[i][j] = MFMA_BF16(af[i], bfr[j], pacc[i][j], 0, 0, 0);
    }
#pragma unroll
    for (int i = 0; i < 2; i++)
#pragma unroll
      for (int j = 0; j < 2; j++)
#pragma unroll
        for (int r = 0; r < 4; r++) {
          int trow = qr + i * 16 + rg + r;
          int scol = qc + j * 16 + fr;
          float v = (scol < trow) ? eta_s * pacc[i][j][r] : 0.0f;
          Ps[trow * LDW + scol] = (__bf16)v;
        }
  }
  __syncthreads();
  {
    f32x4 oacc[2][2];
#pragma unroll
    for (int i = 0; i < 2; i++)
#pragma unroll
      for (int j = 0; j < 2; j++) oacc[i][j] = (f32x4)0.0f;
#pragma unroll
    for (int kk = 0; kk < 2; ++kk) {
      bf16x8 pa[2], vb[2], qa[2], sb[2];
#pragma unroll
      for (int i = 0; i < 2; i++) {
        pa[i] = *(const bf16x8*)(Ps + (qr + i * 16 + fr) * LDW + kk * 32 + kb);
        qa[i] = *(const bf16x8*)(Qs + (qr + i * 16 + fr) * LDW + kk * 32 + kb);
      }
#pragma unroll
      for (int j = 0; j < 2; j++) {
        vb[j] = *(const bf16x8*)(Vt + (qc + j * 16 + fr) * LDW + kk * 32 + kb);
        sb[j] = *(const bf16x8*)(St + (qc + j * 16 + fr) * LDW + kk * 32 + kb);
      }
#pragma unroll
      for (int i = 0; i < 2; i++)
#pragma unroll
        for (int j = 0; j < 2; j++) {
          oacc[i][j] = MFMA_BF16(pa[i], vb[j], oacc[i][j], 0, 0, 0);
          oacc[i][j] = MFMA_BF16(qa[i], sb[j], oacc[i][j], 0, 0, 0);
        }
    }
#pragma unroll
    for (int i = 0; i < 2; i++)
#pragma unroll
      for (int j = 0; j < 2; j++)
#pragma unroll
        for (int r = 0; r < 4; r++) {
          size_t row = row0 + qr + i * 16 + rg + r;
          int col = h * 64 + qc + j * 16 + fr;
          outp[row * C_ + col] = (__bf16)oacc[i][j][r];
        }
  }
}

extern "C" void kernel_launch(void* const* d_in, const int* in_sizes, int n_in,
                              void* d_out, int out_size, void* d_ws, size_t ws_size,
                              hipStream_t stream) {
  const float* x      = (const float*)d_in[0];
  const float* sigma0 = (const float*)d_in[1];
  const float* w_qkv  = (const float*)d_in[2];
  const float* w_proj = (const float*)d_in[3];
  const float* eta    = (const float*)d_in[4];
  float* out       = (float*)d_out;
  float* sigma_out = out + (size_t)M_ * C_;

  char* ws = (char*)d_ws;
  __bf16* xbf     = (__bf16*)(ws);               // 32 MB (reused as out_pre)
  __bf16* wqkvbf  = (__bf16*)(ws + 33554432);
  __bf16* wprojbf = (__bf16*)(ws + 39845888);
  __bf16* qkvbf   = (__bf16*)(ws + 41943040);    // 96 MB
  __bf16* Gws     = (__bf16*)(ws + 142606336);   // 32 MB
  __bf16* Sws     = (__bf16*)(ws + 176160768);   // 32 MB
  float2* tab     = (float2*)(ws + 176160768);   // 1 MB, dead before prefix_scan writes S

  rope_tab<<<512, 256, 0, stream>>>(tab);
  cvt_f32_bf16<<<16384, 256, 0, stream>>>(x, xbf, 4194304);
  cvt_f32_bf16<<<3072, 256, 0, stream>>>(w_qkv, wqkvbf, 786432);
  cvt_f32_bf16<<<1024, 256, 0, stream>>>(w_proj, wprojbf, 262144);
  gemm_dbuf<1><<<dim3(12, 64), 512, 0, stream>>>(xbf, wqkvbf, (void*)qkvbf, tab, N3_);
  chunk_kv<<<4096, 256, 0, stream>>>(qkvbf, Gws);
  prefix_scan<<<256, 256, 0, stream>>>(Gws, sigma0, Sws, sigma_out, eta);
  chunk_out<<<4096, 256, 0, stream>>>(qkvbf, Sws, xbf, eta);
  gemm_dbuf<2><<<dim3(4, 64), 512, 0, stream>>>(xbf, wprojbf, (void*)out, nullptr, C_);
}